// Round 5
// baseline (84.635 us; speedup 1.0000x reference)
//
#include <hip/hip_runtime.h>
#include <hip/hip_bf16.h>

#define STUN   50000
#define BATCH  4096
#define LOG2E  1.4426950408889634f

__device__ __forceinline__ float fexp2(float x){ return __builtin_amdgcn_exp2f(x); }
__device__ __forceinline__ float frcp (float x){ return __builtin_amdgcn_rcpf(x); }
__device__ __forceinline__ float fsig (float x){ return frcp(1.0f + fexp2(-LOG2E * x)); }

// ---------------------------------------------------------------------------
// K0: weight repack (float4-interleaved) + A-matrix precompute.
//   kle4 [u4=16][idx=128][4]  = kle[idx][u4*4+c]
//   fc1i/fc2i [u4=48][128][4] = fcW[idx][u4*4+c]
//   W1ai/W2ai [u4=32][128][4] = W[idx][u4*4+c]        (the 'a' half, u<128)
//   A1JK/A2JK [j=128][k=128]  = -log2e * sum_t kle[k][t]*W[j][128+t]
// grid 432 blocks x 128 threads
// ---------------------------------------------------------------------------
__global__ __launch_bounds__(128) void k_pre(
    const float* __restrict__ kle,
    const float* __restrict__ W1,
    const float* __restrict__ W2,
    const float* __restrict__ fc1_W,
    const float* __restrict__ fc2_W,
    float* __restrict__ kle4,
    float* __restrict__ fc1i,
    float* __restrict__ fc2i,
    float* __restrict__ W1ai,
    float* __restrict__ W2ai,
    float* __restrict__ A1JK,
    float* __restrict__ A2JK)
{
    const int bid = blockIdx.x;
    const int t   = threadIdx.x;   // 0..127
    if (bid < 16) {
        const int u4 = bid;
        float4 v;
        v.x = kle[t * 64 + u4 * 4 + 0];
        v.y = kle[t * 64 + u4 * 4 + 1];
        v.z = kle[t * 64 + u4 * 4 + 2];
        v.w = kle[t * 64 + u4 * 4 + 3];
        *(float4*)&kle4[(u4 * 128 + t) * 4] = v;
    } else if (bid < 64) {
        const int u4 = bid - 16;
        float4 v;
        v.x = fc1_W[t * 192 + u4 * 4 + 0];
        v.y = fc1_W[t * 192 + u4 * 4 + 1];
        v.z = fc1_W[t * 192 + u4 * 4 + 2];
        v.w = fc1_W[t * 192 + u4 * 4 + 3];
        *(float4*)&fc1i[(u4 * 128 + t) * 4] = v;
    } else if (bid < 112) {
        const int u4 = bid - 64;
        float4 v;
        v.x = fc2_W[t * 192 + u4 * 4 + 0];
        v.y = fc2_W[t * 192 + u4 * 4 + 1];
        v.z = fc2_W[t * 192 + u4 * 4 + 2];
        v.w = fc2_W[t * 192 + u4 * 4 + 3];
        *(float4*)&fc2i[(u4 * 128 + t) * 4] = v;
    } else if (bid < 144) {
        const int u4 = bid - 112;
        float4 v;
        v.x = W1[t * 192 + u4 * 4 + 0];
        v.y = W1[t * 192 + u4 * 4 + 1];
        v.z = W1[t * 192 + u4 * 4 + 2];
        v.w = W1[t * 192 + u4 * 4 + 3];
        *(float4*)&W1ai[(u4 * 128 + t) * 4] = v;
    } else if (bid < 176) {
        const int u4 = bid - 144;
        float4 v;
        v.x = W2[t * 192 + u4 * 4 + 0];
        v.y = W2[t * 192 + u4 * 4 + 1];
        v.z = W2[t * 192 + u4 * 4 + 2];
        v.w = W2[t * 192 + u4 * 4 + 3];
        *(float4*)&W2ai[(u4 * 128 + t) * 4] = v;
    } else if (bid < 304) {
        const int j = bid - 176;          // lane t = k
        float acc = 0.f;
        #pragma unroll
        for (int u4 = 0; u4 < 16; ++u4) {
            const float4 kv = *(const float4*)&kle[t * 64 + u4 * 4];
            const float4 wv = *(const float4*)&W1[j * 192 + 128 + u4 * 4];
            acc += kv.x * wv.x + kv.y * wv.y + kv.z * wv.z + kv.w * wv.w;
        }
        A1JK[j * 128 + t] = -LOG2E * acc;   // coalesced store, [j][k]
    } else {
        const int j = bid - 304;
        float acc = 0.f;
        #pragma unroll
        for (int u4 = 0; u4 < 16; ++u4) {
            const float4 kv = *(const float4*)&kle[t * 64 + u4 * 4];
            const float4 wv = *(const float4*)&W2[j * 192 + 128 + u4 * 4];
            acc += kv.x * wv.x + kv.y * wv.y + kv.z * wv.z + kv.w * wv.w;
        }
        A2JK[j * 128 + t] = -LOG2E * acc;
    }
}

// ---------------------------------------------------------------------------
// K_FUSED v2: 4 batch elems/block, 512 threads, grid 1024 -> 4 blocks/CU.
// No A staging: A read directly from global [j][k], coalesced, L2-hot.
// Main loop: wave w -> jh=w>>2 (j-half), kh=(w>>1)&1 (k-half), pr=w&1 (b-pair)
// Paired sigmoid: sig(x1)-sig(x2) = (v-u)/((1+u)(1+v)), u=e^-x1, v=e^-x2
// ---------------------------------------------------------------------------
__global__ __launch_bounds__(512, 8) void k_fused(
    const int*   __restrict__ stu_id,
    const int*   __restrict__ exer_id,
    const float* __restrict__ student_emb,   // (2*50000, 64) flat
    const float* __restrict__ prompt_stu,    // (50000, 64)
    const float* __restrict__ k_diff,        // (20000, 64)
    const float* __restrict__ s_exer,        // (2, 64)
    const float* __restrict__ kle4,
    const float* __restrict__ fc1i,
    const float* __restrict__ fc2i,
    const float* __restrict__ W1ai,
    const float* __restrict__ W2ai,
    const float* __restrict__ fc1_b,
    const float* __restrict__ fc2_b,
    const float* __restrict__ A1JK,   // (128 j, 128 k), pre-scaled by -log2e
    const float* __restrict__ A2JK,
    const float* __restrict__ W3,
    const float* __restrict__ b3,
    const float* __restrict__ kn,
    float* __restrict__ out)
{
    __shared__ __align__(16) float sh_in [4][64][4];    // 4 KB
    __shared__ __align__(16) float sh_old[2][128][4];   // 4 KB
    __shared__ __align__(16) float sh_e  [2][128][4];   // 4 KB
    __shared__ __align__(16) float sh_s  [2][4][128];   // 4 KB
    __shared__ float sW3[128];
    __shared__ float red[8][64][2];                     // 4 KB j-half partials
    __shared__ float red2_o[2][2][2];
    __shared__ float red2_k[2][2][2];

    const int t  = threadIdx.x;           // 0..511
    const int b0 = blockIdx.x * 4;

    // ---- gather phase: 64 threads per local batch elem, coalesced ----
    if (t < 256) {
        const int g   = t >> 6;
        const int u   = t & 63;
        const int sid = stu_id[b0 + g];
        const int eid = exer_id[b0 + g];
        const int er  = (eid >= 10000) ? 1 : 0;
        sh_in[0][u][g] = student_emb[sid * 64 + u];
        sh_in[1][u][g] = fsig(k_diff[eid * 64 + u]);
        sh_in[2][u][g] = prompt_stu[(sid % STUN) * 64 + u];
        sh_in[3][u][g] = fsig(s_exer[er * 64 + u]);
    } else if (t < 288) {
        const int q = t - 256;
        *(float4*)&sW3[q * 4] = *(const float4*)&W3[q * 4];
    }
    __syncthreads();

    const int half = (t >> 7) & 1;
    const int idx  = t & 127;

#define FMA4(xbase) { \
        const float4 x0 = *(const float4*)&(xbase)[0]; \
        acc[0] += wv * x0.x; acc[1] += wv * x0.y; acc[2] += wv * x0.z; acc[3] += wv * x0.w; }

    if (t < 256) {
        // ---- stage 1: old[k] = sig( dot(row, kle[k]) ) ----
        float acc[4];
        #pragma unroll
        for (int b = 0; b < 4; ++b) acc[b] = 0.f;
        #pragma unroll 4
        for (int u4 = 0; u4 < 16; ++u4) {
            const float4 w4 = *(const float4*)&kle4[(u4 * 128 + idx) * 4];
            { const float wv = w4.x; FMA4(sh_in[half][u4*4+0]); }
            { const float wv = w4.y; FMA4(sh_in[half][u4*4+1]); }
            { const float wv = w4.z; FMA4(sh_in[half][u4*4+2]); }
            { const float wv = w4.w; FMA4(sh_in[half][u4*4+3]); }
        }
        #pragma unroll
        for (int b = 0; b < 4; ++b) sh_old[half][idx][b] = fsig(acc[b]);
    }
    __syncthreads();

    if (t < 256) {
        // ---- stage 2: e[i] = sig( [p, old] @ fcW[i] + fcb[i] ) ----
        const float* fcT = half ? fc2i : fc1i;
        const float* fcb = half ? fc2_b : fc1_b;
        float acc[4];
        #pragma unroll
        for (int b = 0; b < 4; ++b) acc[b] = 0.f;
        #pragma unroll 4
        for (int u4 = 0; u4 < 16; ++u4) {
            const float4 w4 = *(const float4*)&fcT[(u4 * 128 + idx) * 4];
            { const float wv = w4.x; FMA4(sh_in[2+half][u4*4+0]); }
            { const float wv = w4.y; FMA4(sh_in[2+half][u4*4+1]); }
            { const float wv = w4.z; FMA4(sh_in[2+half][u4*4+2]); }
            { const float wv = w4.w; FMA4(sh_in[2+half][u4*4+3]); }
        }
        #pragma unroll 4
        for (int u4 = 16; u4 < 48; ++u4) {
            const float4 w4 = *(const float4*)&fcT[(u4 * 128 + idx) * 4];
            const int uo = (u4 - 16) * 4;
            { const float wv = w4.x; FMA4(sh_old[half][uo+0]); }
            { const float wv = w4.y; FMA4(sh_old[half][uo+1]); }
            { const float wv = w4.z; FMA4(sh_old[half][uo+2]); }
            { const float wv = w4.w; FMA4(sh_old[half][uo+3]); }
        }
        const float bias = fcb[idx];
        #pragma unroll
        for (int b = 0; b < 4; ++b) sh_e[half][idx][b] = fsig(acc[b] + bias);
    }
    __syncthreads();

    if (t < 256) {
        // ---- stage 3: s[j] = -log2e * dot(e, Wa[j]) -> sh_s ----
        const float* WT = half ? W2ai : W1ai;
        float acc[4];
        #pragma unroll
        for (int b = 0; b < 4; ++b) acc[b] = 0.f;
        #pragma unroll 4
        for (int u4 = 0; u4 < 32; ++u4) {
            const float4 w4 = *(const float4*)&WT[(u4 * 128 + idx) * 4];
            { const float wv = w4.x; FMA4(sh_e[half][u4*4+0]); }
            { const float wv = w4.y; FMA4(sh_e[half][u4*4+1]); }
            { const float wv = w4.z; FMA4(sh_e[half][u4*4+2]); }
            { const float wv = w4.w; FMA4(sh_e[half][u4*4+3]); }
        }
        #pragma unroll
        for (int b = 0; b < 4; ++b) sh_s[half][b][idx] = -LOG2E * acc[b];
    }
#undef FMA4
    __syncthreads();

    // ---- main loop ----
    const int w   = t >> 6;
    const int kk  = t & 63;
    const int jh  = w >> 2;          // j-half
    const int kh  = (w >> 1) & 1;    // k-half
    const int pr  = w & 1;           // b-pair
    const int k2  = kk + kh * 64;
    const int i0  = pr * 2;
    const int jb  = jh * 64;

    float acc0 = 0.f, acc1 = 0.f;

    #pragma unroll 4
    for (int j4 = 0; j4 < 16; ++j4) {
        const int j = jb + j4 * 4;
        const float4 s1a = *(const float4*)&sh_s[0][i0 + 0][j];
        const float4 s1b = *(const float4*)&sh_s[0][i0 + 1][j];
        const float4 s2a = *(const float4*)&sh_s[1][i0 + 0][j];
        const float4 s2b = *(const float4*)&sh_s[1][i0 + 1][j];
        const float4 w3  = *(const float4*)&sW3[j];
        const float a10 = A1JK[(j + 0) * 128 + k2];
        const float a11 = A1JK[(j + 1) * 128 + k2];
        const float a12 = A1JK[(j + 2) * 128 + k2];
        const float a13 = A1JK[(j + 3) * 128 + k2];
        const float a20 = A2JK[(j + 0) * 128 + k2];
        const float a21 = A2JK[(j + 1) * 128 + k2];
        const float a22 = A2JK[(j + 2) * 128 + k2];
        const float a23 = A2JK[(j + 3) * 128 + k2];

#define SIGPAIR(acc, s1, s2, a1, a2, wv) { \
        const float u = fexp2((s1) + (a1)); \
        const float v = fexp2((s2) + (a2)); \
        const float d = frcp((1.f + u) * (1.f + v)); \
        acc += ((v - u) * d) * (wv); }

        SIGPAIR(acc0, s1a.x, s2a.x, a10, a20, w3.x);
        SIGPAIR(acc0, s1a.y, s2a.y, a11, a21, w3.y);
        SIGPAIR(acc0, s1a.z, s2a.z, a12, a22, w3.z);
        SIGPAIR(acc0, s1a.w, s2a.w, a13, a23, w3.w);
        SIGPAIR(acc1, s1b.x, s2b.x, a10, a20, w3.x);
        SIGPAIR(acc1, s1b.y, s2b.y, a11, a21, w3.y);
        SIGPAIR(acc1, s1b.z, s2b.z, a12, a22, w3.z);
        SIGPAIR(acc1, s1b.w, s2b.w, a13, a23, w3.w);
#undef SIGPAIR
    }

    // ---- epilogue: combine j-halves, outer sigmoid, kn-weighted k-mean ----
    red[w][kk][0] = acc0;
    red[w][kk][1] = acc1;
    __syncthreads();
    if (w < 4) {
        const float bb3 = b3[0];
        const float t0 = acc0 + red[w + 4][kk][0];
        const float t1 = acc1 + red[w + 4][kk][1];
        const float o0 = fsig(t0 + bb3);
        const float o1 = fsig(t1 + bb3);
        const float kn0 = kn[(b0 + i0 + 0) * 128 + k2];
        const float kn1 = kn[(b0 + i0 + 1) * 128 + k2];
        float co0 = o0 * kn0, ck0 = kn0;
        float co1 = o1 * kn1, ck1 = kn1;
        #pragma unroll
        for (int off = 1; off < 64; off <<= 1) {
            co0 += __shfl_xor(co0, off);
            ck0 += __shfl_xor(ck0, off);
            co1 += __shfl_xor(co1, off);
            ck1 += __shfl_xor(ck1, off);
        }
        if (kk == 0) {
            red2_o[kh][pr][0] = co0; red2_o[kh][pr][1] = co1;
            red2_k[kh][pr][0] = ck0; red2_k[kh][pr][1] = ck1;
        }
    }
    __syncthreads();
    if (t < 4) {
        const int b  = t;
        const int p  = b >> 1;
        const int i  = b & 1;
        const float so = red2_o[0][p][i] + red2_o[1][p][i];
        const float sk = red2_k[0][p][i] + red2_k[1][p][i];
        out[b0 + b] = so / sk;
    }
}

// ---------------------------------------------------------------------------
extern "C" void kernel_launch(void* const* d_in, const int* in_sizes, int n_in,
                              void* d_out, int out_size, void* d_ws, size_t ws_size,
                              hipStream_t stream)
{
    const int*   stu_id      = (const int*)  d_in[0];
    const int*   exer_id     = (const int*)  d_in[1];
    const float* kn_emb      = (const float*)d_in[2];
    const float* student_emb = (const float*)d_in[3];
    const float* prompt_stu  = (const float*)d_in[4];
    const float* kle         = (const float*)d_in[5];
    const float* k_diff      = (const float*)d_in[6];
    const float* s_exer      = (const float*)d_in[7];
    const float* W1          = (const float*)d_in[8];
    const float* W2          = (const float*)d_in[9];
    const float* W3          = (const float*)d_in[10];
    const float* b3          = (const float*)d_in[11];
    const float* fc1_W       = (const float*)d_in[12];
    const float* fc1_b       = (const float*)d_in[13];
    const float* fc2_W       = (const float*)d_in[14];
    const float* fc2_b       = (const float*)d_in[15];
    float* out = (float*)d_out;

    float* ws   = (float*)d_ws;
    float* kle4 = ws;                        // 16*128*4  = 8192
    float* fc1i = kle4 + 8192;               // 48*128*4  = 24576
    float* fc2i = fc1i + 24576;
    float* W1ai = fc2i + 24576;              // 32*128*4  = 16384
    float* W2ai = W1ai + 16384;
    float* A1JK = W2ai + 16384;              // 128*128
    float* A2JK = A1JK + 16384;

    k_pre<<<432, 128, 0, stream>>>(kle, W1, W2, fc1_W, fc2_W,
                                   kle4, fc1i, fc2i, W1ai, W2ai, A1JK, A2JK);
    k_fused<<<BATCH / 4, 512, 0, stream>>>(stu_id, exer_id, student_emb, prompt_stu,
                                           k_diff, s_exer, kle4, fc1i, fc2i,
                                           W1ai, W2ai, fc1_b, fc2_b,
                                           A1JK, A2JK, W3, b3, kn_emb, out);
}

// Round 6
// 69.851 us; speedup vs baseline: 1.2116x; 1.2116x over previous
//
#include <hip/hip_runtime.h>
#include <hip/hip_bf16.h>

#define STUN   50000
#define BATCH  4096
#define LOG2E  1.4426950408889634f

__device__ __forceinline__ float fexp2(float x){ return __builtin_amdgcn_exp2f(x); }
__device__ __forceinline__ float frcp (float x){ return __builtin_amdgcn_rcpf(x); }
__device__ __forceinline__ float fsig (float x){ return frcp(1.0f + fexp2(-LOG2E * x)); }

// ---------------------------------------------------------------------------
// K0: weight repack (float4-interleaved) + A-matrix precompute (interleaved).
//   kle4 [u4=16][idx=128][4]  = kle[idx][u4*4+c]
//   fc1i/fc2i [u4=48][128][4] = fcW[idx][u4*4+c]
//   W1ai/W2ai [u4=32][128][4] = W[idx][u4*4+c]        (the 'a' half, u<128)
//   A1i/A2i  [j4=32][k=128][4]= -log2e * sum_t kle[k][t]*W[j4*4+c][128+t]
// grid 432 blocks x 128 threads
// ---------------------------------------------------------------------------
__global__ __launch_bounds__(128) void k_pre(
    const float* __restrict__ kle,
    const float* __restrict__ W1,
    const float* __restrict__ W2,
    const float* __restrict__ fc1_W,
    const float* __restrict__ fc2_W,
    float* __restrict__ kle4,
    float* __restrict__ fc1i,
    float* __restrict__ fc2i,
    float* __restrict__ W1ai,
    float* __restrict__ W2ai,
    float* __restrict__ A1i,
    float* __restrict__ A2i)
{
    const int bid = blockIdx.x;
    const int t   = threadIdx.x;   // 0..127
    if (bid < 16) {
        const int u4 = bid;
        float4 v;
        v.x = kle[t * 64 + u4 * 4 + 0];
        v.y = kle[t * 64 + u4 * 4 + 1];
        v.z = kle[t * 64 + u4 * 4 + 2];
        v.w = kle[t * 64 + u4 * 4 + 3];
        *(float4*)&kle4[(u4 * 128 + t) * 4] = v;
    } else if (bid < 64) {
        const int u4 = bid - 16;
        float4 v;
        v.x = fc1_W[t * 192 + u4 * 4 + 0];
        v.y = fc1_W[t * 192 + u4 * 4 + 1];
        v.z = fc1_W[t * 192 + u4 * 4 + 2];
        v.w = fc1_W[t * 192 + u4 * 4 + 3];
        *(float4*)&fc1i[(u4 * 128 + t) * 4] = v;
    } else if (bid < 112) {
        const int u4 = bid - 64;
        float4 v;
        v.x = fc2_W[t * 192 + u4 * 4 + 0];
        v.y = fc2_W[t * 192 + u4 * 4 + 1];
        v.z = fc2_W[t * 192 + u4 * 4 + 2];
        v.w = fc2_W[t * 192 + u4 * 4 + 3];
        *(float4*)&fc2i[(u4 * 128 + t) * 4] = v;
    } else if (bid < 144) {
        const int u4 = bid - 112;
        float4 v;
        v.x = W1[t * 192 + u4 * 4 + 0];
        v.y = W1[t * 192 + u4 * 4 + 1];
        v.z = W1[t * 192 + u4 * 4 + 2];
        v.w = W1[t * 192 + u4 * 4 + 3];
        *(float4*)&W1ai[(u4 * 128 + t) * 4] = v;
    } else if (bid < 176) {
        const int u4 = bid - 144;
        float4 v;
        v.x = W2[t * 192 + u4 * 4 + 0];
        v.y = W2[t * 192 + u4 * 4 + 1];
        v.z = W2[t * 192 + u4 * 4 + 2];
        v.w = W2[t * 192 + u4 * 4 + 3];
        *(float4*)&W2ai[(u4 * 128 + t) * 4] = v;
    } else if (bid < 304) {
        const int j = bid - 176;          // lane t = k
        float acc = 0.f;
        #pragma unroll
        for (int u4 = 0; u4 < 16; ++u4) {
            const float4 kv = *(const float4*)&kle[t * 64 + u4 * 4];
            const float4 wv = *(const float4*)&W1[j * 192 + 128 + u4 * 4];
            acc += kv.x * wv.x + kv.y * wv.y + kv.z * wv.z + kv.w * wv.w;
        }
        A1i[((j >> 2) * 128 + t) * 4 + (j & 3)] = -LOG2E * acc;
    } else {
        const int j = bid - 304;
        float acc = 0.f;
        #pragma unroll
        for (int u4 = 0; u4 < 16; ++u4) {
            const float4 kv = *(const float4*)&kle[t * 64 + u4 * 4];
            const float4 wv = *(const float4*)&W2[j * 192 + 128 + u4 * 4];
            acc += kv.x * wv.x + kv.y * wv.y + kv.z * wv.z + kv.w * wv.w;
        }
        A2i[((j >> 2) * 128 + t) * 4 + (j & 3)] = -LOG2E * acc;
    }
}

// ---------------------------------------------------------------------------
// K_FUSED v3: 4 batch elems/block, 512 threads, grid 1024.
// launch_bounds(512,6): VGPR cap ~84 -> NO SPILLS, 24 waves/CU.
// A read directly from global, float4-interleaved [j4][k][4], L2-hot.
// Main loop: wave w -> jh=w>>2 (j-half), kh=(w>>1)&1 (k-half), pr=w&1 (b-pair)
// Paired sigmoid: sig(x1)-sig(x2) = (v-u)/((1+u)(1+v)), u=e^-x1, v=e^-x2
// ---------------------------------------------------------------------------
__global__ __launch_bounds__(512, 6) void k_fused(
    const int*   __restrict__ stu_id,
    const int*   __restrict__ exer_id,
    const float* __restrict__ student_emb,   // (2*50000, 64) flat
    const float* __restrict__ prompt_stu,    // (50000, 64)
    const float* __restrict__ k_diff,        // (20000, 64)
    const float* __restrict__ s_exer,        // (2, 64)
    const float* __restrict__ kle4,
    const float* __restrict__ fc1i,
    const float* __restrict__ fc2i,
    const float* __restrict__ W1ai,
    const float* __restrict__ W2ai,
    const float* __restrict__ fc1_b,
    const float* __restrict__ fc2_b,
    const float* __restrict__ A1i,    // [j4=32][k=128][4], pre-scaled -log2e
    const float* __restrict__ A2i,
    const float* __restrict__ W3,
    const float* __restrict__ b3,
    const float* __restrict__ kn,
    float* __restrict__ out)
{
    __shared__ __align__(16) float sh_in [4][64][4];    // 4 KB
    __shared__ __align__(16) float sh_old[2][128][4];   // 4 KB
    __shared__ __align__(16) float sh_e  [2][128][4];   // 4 KB
    __shared__ __align__(16) float sh_s  [2][4][128];   // 4 KB
    __shared__ float sW3[128];
    __shared__ float red[8][64][2];                     // 4 KB j-half partials
    __shared__ float red2_o[2][2][2];
    __shared__ float red2_k[2][2][2];

    const int t  = threadIdx.x;           // 0..511
    const int b0 = blockIdx.x * 4;

    // ---- gather phase: 64 threads per local batch elem, coalesced ----
    if (t < 256) {
        const int g   = t >> 6;
        const int u   = t & 63;
        const int sid = stu_id[b0 + g];
        const int eid = exer_id[b0 + g];
        const int er  = (eid >= 10000) ? 1 : 0;
        sh_in[0][u][g] = student_emb[sid * 64 + u];
        sh_in[1][u][g] = fsig(k_diff[eid * 64 + u]);
        sh_in[2][u][g] = prompt_stu[(sid % STUN) * 64 + u];
        sh_in[3][u][g] = fsig(s_exer[er * 64 + u]);
    } else if (t < 288) {
        const int q = t - 256;
        *(float4*)&sW3[q * 4] = *(const float4*)&W3[q * 4];
    }
    __syncthreads();

    const int half = (t >> 7) & 1;
    const int idx  = t & 127;

#define FMA4(xbase) { \
        const float4 x0 = *(const float4*)&(xbase)[0]; \
        acc[0] += wv * x0.x; acc[1] += wv * x0.y; acc[2] += wv * x0.z; acc[3] += wv * x0.w; }

    if (t < 256) {
        // ---- stage 1: old[k] = sig( dot(row, kle[k]) ) ----
        float acc[4];
        #pragma unroll
        for (int b = 0; b < 4; ++b) acc[b] = 0.f;
        #pragma unroll 4
        for (int u4 = 0; u4 < 16; ++u4) {
            const float4 w4 = *(const float4*)&kle4[(u4 * 128 + idx) * 4];
            { const float wv = w4.x; FMA4(sh_in[half][u4*4+0]); }
            { const float wv = w4.y; FMA4(sh_in[half][u4*4+1]); }
            { const float wv = w4.z; FMA4(sh_in[half][u4*4+2]); }
            { const float wv = w4.w; FMA4(sh_in[half][u4*4+3]); }
        }
        #pragma unroll
        for (int b = 0; b < 4; ++b) sh_old[half][idx][b] = fsig(acc[b]);
    }
    __syncthreads();

    if (t < 256) {
        // ---- stage 2: e[i] = sig( [p, old] @ fcW[i] + fcb[i] ) ----
        const float* fcT = half ? fc2i : fc1i;
        const float* fcb = half ? fc2_b : fc1_b;
        float acc[4];
        #pragma unroll
        for (int b = 0; b < 4; ++b) acc[b] = 0.f;
        #pragma unroll 4
        for (int u4 = 0; u4 < 16; ++u4) {
            const float4 w4 = *(const float4*)&fcT[(u4 * 128 + idx) * 4];
            { const float wv = w4.x; FMA4(sh_in[2+half][u4*4+0]); }
            { const float wv = w4.y; FMA4(sh_in[2+half][u4*4+1]); }
            { const float wv = w4.z; FMA4(sh_in[2+half][u4*4+2]); }
            { const float wv = w4.w; FMA4(sh_in[2+half][u4*4+3]); }
        }
        #pragma unroll 4
        for (int u4 = 16; u4 < 48; ++u4) {
            const float4 w4 = *(const float4*)&fcT[(u4 * 128 + idx) * 4];
            const int uo = (u4 - 16) * 4;
            { const float wv = w4.x; FMA4(sh_old[half][uo+0]); }
            { const float wv = w4.y; FMA4(sh_old[half][uo+1]); }
            { const float wv = w4.z; FMA4(sh_old[half][uo+2]); }
            { const float wv = w4.w; FMA4(sh_old[half][uo+3]); }
        }
        const float bias = fcb[idx];
        #pragma unroll
        for (int b = 0; b < 4; ++b) sh_e[half][idx][b] = fsig(acc[b] + bias);
    }
    __syncthreads();

    if (t < 256) {
        // ---- stage 3: s[j] = -log2e * dot(e, Wa[j]) -> sh_s ----
        const float* WT = half ? W2ai : W1ai;
        float acc[4];
        #pragma unroll
        for (int b = 0; b < 4; ++b) acc[b] = 0.f;
        #pragma unroll 4
        for (int u4 = 0; u4 < 32; ++u4) {
            const float4 w4 = *(const float4*)&WT[(u4 * 128 + idx) * 4];
            { const float wv = w4.x; FMA4(sh_e[half][u4*4+0]); }
            { const float wv = w4.y; FMA4(sh_e[half][u4*4+1]); }
            { const float wv = w4.z; FMA4(sh_e[half][u4*4+2]); }
            { const float wv = w4.w; FMA4(sh_e[half][u4*4+3]); }
        }
        #pragma unroll
        for (int b = 0; b < 4; ++b) sh_s[half][b][idx] = -LOG2E * acc[b];
    }
#undef FMA4
    __syncthreads();

    // ---- main loop ----
    const int w   = t >> 6;
    const int kk  = t & 63;
    const int jh  = w >> 2;          // j-half
    const int kh  = (w >> 1) & 1;    // k-half
    const int pr  = w & 1;           // b-pair
    const int k2  = kk + kh * 64;
    const int i0  = pr * 2;

    const float4* A1v = (const float4*)A1i + (jh * 16) * 128 + k2;
    const float4* A2v = (const float4*)A2i + (jh * 16) * 128 + k2;

    float acc0 = 0.f, acc1 = 0.f;

    #pragma unroll 2
    for (int j4 = 0; j4 < 16; ++j4) {
        const int j = jh * 64 + j4 * 4;
        const float4 a1  = A1v[j4 * 128];
        const float4 a2  = A2v[j4 * 128];
        const float4 s1a = *(const float4*)&sh_s[0][i0 + 0][j];
        const float4 s1b = *(const float4*)&sh_s[0][i0 + 1][j];
        const float4 s2a = *(const float4*)&sh_s[1][i0 + 0][j];
        const float4 s2b = *(const float4*)&sh_s[1][i0 + 1][j];
        const float4 w3  = *(const float4*)&sW3[j];

#define SIGPAIR(acc, s1, s2, a1c, a2c, wv) { \
        const float u = fexp2((s1) + (a1c)); \
        const float v = fexp2((s2) + (a2c)); \
        const float d = frcp((1.f + u) * (1.f + v)); \
        acc += ((v - u) * d) * (wv); }

        SIGPAIR(acc0, s1a.x, s2a.x, a1.x, a2.x, w3.x);
        SIGPAIR(acc0, s1a.y, s2a.y, a1.y, a2.y, w3.y);
        SIGPAIR(acc0, s1a.z, s2a.z, a1.z, a2.z, w3.z);
        SIGPAIR(acc0, s1a.w, s2a.w, a1.w, a2.w, w3.w);
        SIGPAIR(acc1, s1b.x, s2b.x, a1.x, a2.x, w3.x);
        SIGPAIR(acc1, s1b.y, s2b.y, a1.y, a2.y, w3.y);
        SIGPAIR(acc1, s1b.z, s2b.z, a1.z, a2.z, w3.z);
        SIGPAIR(acc1, s1b.w, s2b.w, a1.w, a2.w, w3.w);
#undef SIGPAIR
    }

    // ---- epilogue: combine j-halves, outer sigmoid, kn-weighted k-mean ----
    red[w][kk][0] = acc0;
    red[w][kk][1] = acc1;
    __syncthreads();
    if (w < 4) {
        const float bb3 = b3[0];
        const float t0 = acc0 + red[w + 4][kk][0];
        const float t1 = acc1 + red[w + 4][kk][1];
        const float o0 = fsig(t0 + bb3);
        const float o1 = fsig(t1 + bb3);
        const float kn0 = kn[(b0 + i0 + 0) * 128 + k2];
        const float kn1 = kn[(b0 + i0 + 1) * 128 + k2];
        float co0 = o0 * kn0, ck0 = kn0;
        float co1 = o1 * kn1, ck1 = kn1;
        #pragma unroll
        for (int off = 1; off < 64; off <<= 1) {
            co0 += __shfl_xor(co0, off);
            ck0 += __shfl_xor(ck0, off);
            co1 += __shfl_xor(co1, off);
            ck1 += __shfl_xor(ck1, off);
        }
        if (kk == 0) {
            red2_o[kh][pr][0] = co0; red2_o[kh][pr][1] = co1;
            red2_k[kh][pr][0] = ck0; red2_k[kh][pr][1] = ck1;
        }
    }
    __syncthreads();
    if (t < 4) {
        const int b  = t;
        const int p  = b >> 1;
        const int i  = b & 1;
        const float so = red2_o[0][p][i] + red2_o[1][p][i];
        const float sk = red2_k[0][p][i] + red2_k[1][p][i];
        out[b0 + b] = so / sk;
    }
}

// ---------------------------------------------------------------------------
extern "C" void kernel_launch(void* const* d_in, const int* in_sizes, int n_in,
                              void* d_out, int out_size, void* d_ws, size_t ws_size,
                              hipStream_t stream)
{
    const int*   stu_id      = (const int*)  d_in[0];
    const int*   exer_id     = (const int*)  d_in[1];
    const float* kn_emb      = (const float*)d_in[2];
    const float* student_emb = (const float*)d_in[3];
    const float* prompt_stu  = (const float*)d_in[4];
    const float* kle         = (const float*)d_in[5];
    const float* k_diff      = (const float*)d_in[6];
    const float* s_exer      = (const float*)d_in[7];
    const float* W1          = (const float*)d_in[8];
    const float* W2          = (const float*)d_in[9];
    const float* W3          = (const float*)d_in[10];
    const float* b3          = (const float*)d_in[11];
    const float* fc1_W       = (const float*)d_in[12];
    const float* fc1_b       = (const float*)d_in[13];
    const float* fc2_W       = (const float*)d_in[14];
    const float* fc2_b       = (const float*)d_in[15];
    float* out = (float*)d_out;

    float* ws   = (float*)d_ws;
    float* kle4 = ws;                        // 16*128*4  = 8192
    float* fc1i = kle4 + 8192;               // 48*128*4  = 24576
    float* fc2i = fc1i + 24576;
    float* W1ai = fc2i + 24576;              // 32*128*4  = 16384
    float* W2ai = W1ai + 16384;
    float* A1i  = W2ai + 16384;              // 32*128*4  = 16384
    float* A2i  = A1i  + 16384;

    k_pre<<<432, 128, 0, stream>>>(kle, W1, W2, fc1_W, fc2_W,
                                   kle4, fc1i, fc2i, W1ai, W2ai, A1i, A2i);
    k_fused<<<BATCH / 4, 512, 0, stream>>>(stu_id, exer_id, student_emb, prompt_stu,
                                           k_diff, s_exer, kle4, fc1i, fc2i,
                                           W1ai, W2ai, fc1_b, fc2_b,
                                           A1i, A2i, W3, b3, kn_emb, out);
}

// Round 7
// 53.892 us; speedup vs baseline: 1.5704x; 1.2961x over previous
//
#include <hip/hip_runtime.h>
#include <hip/hip_bf16.h>

#define STUN   50000
#define BATCH  4096
#define LOG2E  1.4426950408889634f

__device__ __forceinline__ float fexp2(float x){ return __builtin_amdgcn_exp2f(x); }
__device__ __forceinline__ float frcp (float x){ return __builtin_amdgcn_rcpf(x); }
__device__ __forceinline__ float fsig (float x){ return frcp(1.0f + fexp2(-LOG2E * x)); }

// ---------------------------------------------------------------------------
// K0: weight repack (float4-interleaved) + A-matrix precompute (interleaved).
//   kle4 [u4=16][idx=128][4]  = kle[idx][u4*4+c]
//   fc1i/fc2i [u4=48][128][4] = fcW[idx][u4*4+c]
//   W1ai/W2ai [u4=32][128][4] = W[idx][u4*4+c]        (the 'a' half, u<128)
//   A1i/A2i  [j4=32][k=128][4]= -log2e * sum_t kle[k][t]*W[j4*4+c][128+t]
// grid 432 blocks x 128 threads
// ---------------------------------------------------------------------------
__global__ __launch_bounds__(128) void k_pre(
    const float* __restrict__ kle,
    const float* __restrict__ W1,
    const float* __restrict__ W2,
    const float* __restrict__ fc1_W,
    const float* __restrict__ fc2_W,
    float* __restrict__ kle4,
    float* __restrict__ fc1i,
    float* __restrict__ fc2i,
    float* __restrict__ W1ai,
    float* __restrict__ W2ai,
    float* __restrict__ A1i,
    float* __restrict__ A2i)
{
    const int bid = blockIdx.x;
    const int t   = threadIdx.x;   // 0..127
    if (bid < 16) {
        const int u4 = bid;
        float4 v;
        v.x = kle[t * 64 + u4 * 4 + 0];
        v.y = kle[t * 64 + u4 * 4 + 1];
        v.z = kle[t * 64 + u4 * 4 + 2];
        v.w = kle[t * 64 + u4 * 4 + 3];
        *(float4*)&kle4[(u4 * 128 + t) * 4] = v;
    } else if (bid < 64) {
        const int u4 = bid - 16;
        float4 v;
        v.x = fc1_W[t * 192 + u4 * 4 + 0];
        v.y = fc1_W[t * 192 + u4 * 4 + 1];
        v.z = fc1_W[t * 192 + u4 * 4 + 2];
        v.w = fc1_W[t * 192 + u4 * 4 + 3];
        *(float4*)&fc1i[(u4 * 128 + t) * 4] = v;
    } else if (bid < 112) {
        const int u4 = bid - 64;
        float4 v;
        v.x = fc2_W[t * 192 + u4 * 4 + 0];
        v.y = fc2_W[t * 192 + u4 * 4 + 1];
        v.z = fc2_W[t * 192 + u4 * 4 + 2];
        v.w = fc2_W[t * 192 + u4 * 4 + 3];
        *(float4*)&fc2i[(u4 * 128 + t) * 4] = v;
    } else if (bid < 144) {
        const int u4 = bid - 112;
        float4 v;
        v.x = W1[t * 192 + u4 * 4 + 0];
        v.y = W1[t * 192 + u4 * 4 + 1];
        v.z = W1[t * 192 + u4 * 4 + 2];
        v.w = W1[t * 192 + u4 * 4 + 3];
        *(float4*)&W1ai[(u4 * 128 + t) * 4] = v;
    } else if (bid < 176) {
        const int u4 = bid - 144;
        float4 v;
        v.x = W2[t * 192 + u4 * 4 + 0];
        v.y = W2[t * 192 + u4 * 4 + 1];
        v.z = W2[t * 192 + u4 * 4 + 2];
        v.w = W2[t * 192 + u4 * 4 + 3];
        *(float4*)&W2ai[(u4 * 128 + t) * 4] = v;
    } else if (bid < 304) {
        const int j = bid - 176;          // lane t = k
        float acc = 0.f;
        #pragma unroll
        for (int u4 = 0; u4 < 16; ++u4) {
            const float4 kv = *(const float4*)&kle[t * 64 + u4 * 4];
            const float4 wv = *(const float4*)&W1[j * 192 + 128 + u4 * 4];
            acc += kv.x * wv.x + kv.y * wv.y + kv.z * wv.z + kv.w * wv.w;
        }
        A1i[((j >> 2) * 128 + t) * 4 + (j & 3)] = -LOG2E * acc;
    } else {
        const int j = bid - 304;
        float acc = 0.f;
        #pragma unroll
        for (int u4 = 0; u4 < 16; ++u4) {
            const float4 kv = *(const float4*)&kle[t * 64 + u4 * 4];
            const float4 wv = *(const float4*)&W2[j * 192 + 128 + u4 * 4];
            acc += kv.x * wv.x + kv.y * wv.y + kv.z * wv.z + kv.w * wv.w;
        }
        A2i[((j >> 2) * 128 + t) * 4 + (j & 3)] = -LOG2E * acc;
    }
}

// ---------------------------------------------------------------------------
// K_FUSED v4: 8 batch elems/block, 512 threads, grid 512 (2 blocks/CU).
// Prep uses ALL 512 threads: ug = t>>8 splits the u-accumulation range;
// ug1 writes partials to ps[], ug0 combines + sigmoid. Weights read once.
// Main: wave w -> jh=w>>2, kh=(w>>1)&1, bq=w&1; thread: 4 b x 64 j.
// A f4 loaded once per j4, reused across 4 batch elems.
// Paired sigmoid: sig(x1)-sig(x2) = (v-u)/((1+u)(1+v)), u=e^-x1, v=e^-x2
// ---------------------------------------------------------------------------
__global__ __launch_bounds__(512, 4) void k_fused(
    const int*   __restrict__ stu_id,
    const int*   __restrict__ exer_id,
    const float* __restrict__ student_emb,   // (2*50000, 64) flat
    const float* __restrict__ prompt_stu,    // (50000, 64)
    const float* __restrict__ k_diff,        // (20000, 64)
    const float* __restrict__ s_exer,        // (2, 64)
    const float* __restrict__ kle4,
    const float* __restrict__ fc1i,
    const float* __restrict__ fc2i,
    const float* __restrict__ W1ai,
    const float* __restrict__ W2ai,
    const float* __restrict__ fc1_b,
    const float* __restrict__ fc2_b,
    const float* __restrict__ A1i,    // [j4=32][k=128][4], pre-scaled -log2e
    const float* __restrict__ A2i,
    const float* __restrict__ W3,
    const float* __restrict__ b3,
    const float* __restrict__ kn,
    float* __restrict__ out)
{
    __shared__ __align__(16) float sh_in [4][64][8];    // 8 KB
    __shared__ __align__(16) float sh_old[2][128][8];   // 8 KB
    __shared__ __align__(16) float sh_e  [2][128][8];   // 8 KB
    __shared__ __align__(16) float sh_s  [2][8][128];   // 8 KB  [mat][b][j]
    __shared__ __align__(16) float ps    [2][8][128];   // 4 KB  [half][b][idx]
    __shared__ float sW3[128];
    __shared__ __align__(16) float red[8][64][4];       // 8 KB
    __shared__ float red2_o[2][2][4];
    __shared__ float red2_k[2][2][4];

    const int t  = threadIdx.x;           // 0..511
    const int b0 = blockIdx.x * 8;

    // ---- gather phase: 64 threads per local batch elem, coalesced ----
    {
        const int g   = t >> 6;
        const int u   = t & 63;
        const int sid = stu_id[b0 + g];
        const int eid = exer_id[b0 + g];
        const int er  = (eid >= 10000) ? 1 : 0;
        sh_in[0][u][g] = student_emb[sid * 64 + u];
        sh_in[1][u][g] = fsig(k_diff[eid * 64 + u]);
        sh_in[2][u][g] = prompt_stu[(sid % STUN) * 64 + u];
        sh_in[3][u][g] = fsig(s_exer[er * 64 + u]);
    }
    if (t < 32) *(float4*)&sW3[t * 4] = *(const float4*)&W3[t * 4];
    __syncthreads();

    const int ug   = t >> 8;              // u-range group
    const int tt   = t & 255;
    const int half = tt >> 7;
    const int idx  = tt & 127;

    float acc[8];

#define FMA8(xbase) { \
        const float4 x0 = *(const float4*)&(xbase)[0]; \
        const float4 x1 = *(const float4*)&(xbase)[4]; \
        acc[0] += wv * x0.x; acc[1] += wv * x0.y; acc[2] += wv * x0.z; acc[3] += wv * x0.w; \
        acc[4] += wv * x1.x; acc[5] += wv * x1.y; acc[6] += wv * x1.z; acc[7] += wv * x1.w; }

#define WSTEP(WARR, XARR, u4) { \
        const float4 w4 = *(const float4*)&WARR[((u4) * 128 + idx) * 4]; \
        { const float wv = w4.x; FMA8(XARR[(u4)*4+0]); } \
        { const float wv = w4.y; FMA8(XARR[(u4)*4+1]); } \
        { const float wv = w4.z; FMA8(XARR[(u4)*4+2]); } \
        { const float wv = w4.w; FMA8(XARR[(u4)*4+3]); } }

#define WSTEPO(WARR, XARR, u4, uoff) { \
        const float4 w4 = *(const float4*)&WARR[((u4) * 128 + idx) * 4]; \
        { const float wv = w4.x; FMA8(XARR[((u4)-(uoff))*4+0]); } \
        { const float wv = w4.y; FMA8(XARR[((u4)-(uoff))*4+1]); } \
        { const float wv = w4.z; FMA8(XARR[((u4)-(uoff))*4+2]); } \
        { const float wv = w4.w; FMA8(XARR[((u4)-(uoff))*4+3]); } }

    // ---- stage 1: old[k] = sig( dot(row, kle[k]) ), u-split ----
    #pragma unroll
    for (int b = 0; b < 8; ++b) acc[b] = 0.f;
    {
        const int u4a = ug * 8;
        #pragma unroll 4
        for (int u4 = u4a; u4 < u4a + 8; ++u4) WSTEP(kle4, sh_in[half], u4);
    }
    if (ug == 1) {
        #pragma unroll
        for (int b = 0; b < 8; ++b) ps[half][b][idx] = acc[b];
    }
    __syncthreads();
    if (ug == 0) {
        #pragma unroll
        for (int b = 0; b < 8; ++b)
            sh_old[half][idx][b] = fsig(acc[b] + ps[half][b][idx]);
    }
    __syncthreads();

    // ---- stage 2: e[i] = sig( [p, old] @ fcW[i] + fcb[i] ), u-split ----
    #pragma unroll
    for (int b = 0; b < 8; ++b) acc[b] = 0.f;
    {
        const float* fcT = half ? fc2i : fc1i;
        if (ug == 0) {
            #pragma unroll 4
            for (int u4 = 0; u4 < 16; ++u4) WSTEP(fcT, sh_in[2 + half], u4);
            #pragma unroll 4
            for (int u4 = 16; u4 < 24; ++u4) WSTEPO(fcT, sh_old[half], u4, 16);
        } else {
            #pragma unroll 4
            for (int u4 = 24; u4 < 48; ++u4) WSTEPO(fcT, sh_old[half], u4, 16);
        }
    }
    if (ug == 1) {
        #pragma unroll
        for (int b = 0; b < 8; ++b) ps[half][b][idx] = acc[b];
    }
    __syncthreads();
    if (ug == 0) {
        const float bias = (half ? fc2_b : fc1_b)[idx];
        #pragma unroll
        for (int b = 0; b < 8; ++b)
            sh_e[half][idx][b] = fsig(acc[b] + ps[half][b][idx] + bias);
    }
    __syncthreads();

    // ---- stage 3: s[j] = -log2e * dot(e, Wa[j]), u-split -> sh_s[mat][b][j] ----
    #pragma unroll
    for (int b = 0; b < 8; ++b) acc[b] = 0.f;
    {
        const float* WT = half ? W2ai : W1ai;
        const int u4a = ug * 16;
        #pragma unroll 4
        for (int u4 = u4a; u4 < u4a + 16; ++u4) WSTEP(WT, sh_e[half], u4);
    }
    if (ug == 1) {
        #pragma unroll
        for (int b = 0; b < 8; ++b) ps[half][b][idx] = acc[b];
    }
    __syncthreads();
    if (ug == 0) {
        #pragma unroll
        for (int b = 0; b < 8; ++b)
            sh_s[half][b][idx] = -LOG2E * (acc[b] + ps[half][b][idx]);
    }
#undef FMA8
#undef WSTEP
#undef WSTEPO
    __syncthreads();

    // ---- main loop: wave w -> (jh, kh, bq); thread: 4 b x 64 j ----
    const int w   = t >> 6;
    const int kk  = t & 63;
    const int jh  = w >> 2;          // j-half
    const int kh  = (w >> 1) & 1;    // k-half
    const int bq  = w & 1;           // b-quad
    const int k2  = kk + kh * 64;
    const int ib  = bq * 4;          // local b base

    const float4* A1v = (const float4*)A1i + (jh * 16) * 128 + k2;
    const float4* A2v = (const float4*)A2i + (jh * 16) * 128 + k2;

    float ac0 = 0.f, ac1 = 0.f, ac2 = 0.f, ac3 = 0.f;

    #pragma unroll 2
    for (int j4 = 0; j4 < 16; ++j4) {
        const int j = jh * 64 + j4 * 4;
        const float4 a1 = A1v[j4 * 128];
        const float4 a2 = A2v[j4 * 128];
        const float4 w3 = *(const float4*)&sW3[j];

#define SIGPAIR(acc, s1, s2, a1c, a2c, wv) { \
        const float uu = fexp2((s1) + (a1c)); \
        const float vv = fexp2((s2) + (a2c)); \
        const float dd = frcp((1.f + uu) * (1.f + vv)); \
        acc += ((vv - uu) * dd) * (wv); }

#define BODY(acc, bi) { \
        const float4 s1 = *(const float4*)&sh_s[0][ib + bi][j]; \
        const float4 s2 = *(const float4*)&sh_s[1][ib + bi][j]; \
        SIGPAIR(acc, s1.x, s2.x, a1.x, a2.x, w3.x); \
        SIGPAIR(acc, s1.y, s2.y, a1.y, a2.y, w3.y); \
        SIGPAIR(acc, s1.z, s2.z, a1.z, a2.z, w3.z); \
        SIGPAIR(acc, s1.w, s2.w, a1.w, a2.w, w3.w); }

        BODY(ac0, 0);
        BODY(ac1, 1);
        BODY(ac2, 2);
        BODY(ac3, 3);
#undef BODY
#undef SIGPAIR
    }

    // ---- epilogue: combine j-halves, outer sigmoid, kn-weighted k-mean ----
    red[w][kk][0] = ac0; red[w][kk][1] = ac1;
    red[w][kk][2] = ac2; red[w][kk][3] = ac3;
    __syncthreads();
    if (w < 4) {
        const float bb3 = b3[0];
        const float4 other = *(const float4*)&red[w + 4][kk][0];
        float to[4] = { ac0 + other.x, ac1 + other.y, ac2 + other.z, ac3 + other.w };
        float co[4], ck[4];
        #pragma unroll
        for (int i = 0; i < 4; ++i) {
            const float o   = fsig(to[i] + bb3);
            const float knv = kn[(b0 + ib + i) * 128 + k2];
            co[i] = o * knv;
            ck[i] = knv;
        }
        #pragma unroll
        for (int off = 1; off < 64; off <<= 1) {
            #pragma unroll
            for (int i = 0; i < 4; ++i) {
                co[i] += __shfl_xor(co[i], off);
                ck[i] += __shfl_xor(ck[i], off);
            }
        }
        if (kk == 0) {
            #pragma unroll
            for (int i = 0; i < 4; ++i) {
                red2_o[kh][bq][i] = co[i];
                red2_k[kh][bq][i] = ck[i];
            }
        }
    }
    __syncthreads();
    if (t < 8) {
        const int b  = t;
        const int q  = b >> 2;
        const int i  = b & 3;
        const float so = red2_o[0][q][i] + red2_o[1][q][i];
        const float sk = red2_k[0][q][i] + red2_k[1][q][i];
        out[b0 + b] = so / sk;
    }
}

// ---------------------------------------------------------------------------
extern "C" void kernel_launch(void* const* d_in, const int* in_sizes, int n_in,
                              void* d_out, int out_size, void* d_ws, size_t ws_size,
                              hipStream_t stream)
{
    const int*   stu_id      = (const int*)  d_in[0];
    const int*   exer_id     = (const int*)  d_in[1];
    const float* kn_emb      = (const float*)d_in[2];
    const float* student_emb = (const float*)d_in[3];
    const float* prompt_stu  = (const float*)d_in[4];
    const float* kle         = (const float*)d_in[5];
    const float* k_diff      = (const float*)d_in[6];
    const float* s_exer      = (const float*)d_in[7];
    const float* W1          = (const float*)d_in[8];
    const float* W2          = (const float*)d_in[9];
    const float* W3          = (const float*)d_in[10];
    const float* b3          = (const float*)d_in[11];
    const float* fc1_W       = (const float*)d_in[12];
    const float* fc1_b       = (const float*)d_in[13];
    const float* fc2_W       = (const float*)d_in[14];
    const float* fc2_b       = (const float*)d_in[15];
    float* out = (float*)d_out;

    float* ws   = (float*)d_ws;
    float* kle4 = ws;                        // 16*128*4  = 8192
    float* fc1i = kle4 + 8192;               // 48*128*4  = 24576
    float* fc2i = fc1i + 24576;
    float* W1ai = fc2i + 24576;              // 32*128*4  = 16384
    float* W2ai = W1ai + 16384;
    float* A1i  = W2ai + 16384;              // 32*128*4  = 16384
    float* A2i  = A1i  + 16384;

    k_pre<<<432, 128, 0, stream>>>(kle, W1, W2, fc1_W, fc2_W,
                                   kle4, fc1i, fc2i, W1ai, W2ai, A1i, A2i);
    k_fused<<<BATCH / 8, 512, 0, stream>>>(stu_id, exer_id, student_emb, prompt_stu,
                                           k_diff, s_exer, kle4, fc1i, fc2i,
                                           W1ai, W2ai, fc1_b, fc2_b,
                                           A1i, A2i, W3, b3, kn_emb, out);
}

// Round 8
// 51.539 us; speedup vs baseline: 1.6421x; 1.0457x over previous
//
#include <hip/hip_runtime.h>
#include <hip/hip_bf16.h>

#define STUN   50000
#define BATCH  4096
#define LOG2E  1.4426950408889634f

__device__ __forceinline__ float fexp2(float x){ return __builtin_amdgcn_exp2f(x); }
__device__ __forceinline__ float frcp (float x){ return __builtin_amdgcn_rcpf(x); }
__device__ __forceinline__ float fsig (float x){ return frcp(1.0f + fexp2(-LOG2E * x)); }

// ---------------------------------------------------------------------------
// K0: weight repack (float4-interleaved) + E-matrix precompute (interleaved).
//   kle4 [u4=16][idx=128][4]  = kle[idx][u4*4+c]
//   fc1i/fc2i [u4=48][128][4] = fcW[idx][u4*4+c]
//   W1ai/W2ai [u4=32][128][4] = W[idx][u4*4+c]        (the 'a' half, u<128)
//   E1i/E2i  [j4=32][k=128][4]= exp2(-log2e * sum_t kle[k][t]*W[j4*4+c][128+t])
// grid 432 blocks x 128 threads
// ---------------------------------------------------------------------------
__global__ __launch_bounds__(128) void k_pre(
    const float* __restrict__ kle,
    const float* __restrict__ W1,
    const float* __restrict__ W2,
    const float* __restrict__ fc1_W,
    const float* __restrict__ fc2_W,
    float* __restrict__ kle4,
    float* __restrict__ fc1i,
    float* __restrict__ fc2i,
    float* __restrict__ W1ai,
    float* __restrict__ W2ai,
    float* __restrict__ E1i,
    float* __restrict__ E2i)
{
    const int bid = blockIdx.x;
    const int t   = threadIdx.x;   // 0..127
    if (bid < 16) {
        const int u4 = bid;
        float4 v;
        v.x = kle[t * 64 + u4 * 4 + 0];
        v.y = kle[t * 64 + u4 * 4 + 1];
        v.z = kle[t * 64 + u4 * 4 + 2];
        v.w = kle[t * 64 + u4 * 4 + 3];
        *(float4*)&kle4[(u4 * 128 + t) * 4] = v;
    } else if (bid < 64) {
        const int u4 = bid - 16;
        float4 v;
        v.x = fc1_W[t * 192 + u4 * 4 + 0];
        v.y = fc1_W[t * 192 + u4 * 4 + 1];
        v.z = fc1_W[t * 192 + u4 * 4 + 2];
        v.w = fc1_W[t * 192 + u4 * 4 + 3];
        *(float4*)&fc1i[(u4 * 128 + t) * 4] = v;
    } else if (bid < 112) {
        const int u4 = bid - 64;
        float4 v;
        v.x = fc2_W[t * 192 + u4 * 4 + 0];
        v.y = fc2_W[t * 192 + u4 * 4 + 1];
        v.z = fc2_W[t * 192 + u4 * 4 + 2];
        v.w = fc2_W[t * 192 + u4 * 4 + 3];
        *(float4*)&fc2i[(u4 * 128 + t) * 4] = v;
    } else if (bid < 144) {
        const int u4 = bid - 112;
        float4 v;
        v.x = W1[t * 192 + u4 * 4 + 0];
        v.y = W1[t * 192 + u4 * 4 + 1];
        v.z = W1[t * 192 + u4 * 4 + 2];
        v.w = W1[t * 192 + u4 * 4 + 3];
        *(float4*)&W1ai[(u4 * 128 + t) * 4] = v;
    } else if (bid < 176) {
        const int u4 = bid - 144;
        float4 v;
        v.x = W2[t * 192 + u4 * 4 + 0];
        v.y = W2[t * 192 + u4 * 4 + 1];
        v.z = W2[t * 192 + u4 * 4 + 2];
        v.w = W2[t * 192 + u4 * 4 + 3];
        *(float4*)&W2ai[(u4 * 128 + t) * 4] = v;
    } else if (bid < 304) {
        const int j = bid - 176;          // lane t = k
        float acc = 0.f;
        #pragma unroll
        for (int u4 = 0; u4 < 16; ++u4) {
            const float4 kv = *(const float4*)&kle[t * 64 + u4 * 4];
            const float4 wv = *(const float4*)&W1[j * 192 + 128 + u4 * 4];
            acc += kv.x * wv.x + kv.y * wv.y + kv.z * wv.z + kv.w * wv.w;
        }
        E1i[((j >> 2) * 128 + t) * 4 + (j & 3)] = fexp2(-LOG2E * acc);
    } else {
        const int j = bid - 304;
        float acc = 0.f;
        #pragma unroll
        for (int u4 = 0; u4 < 16; ++u4) {
            const float4 kv = *(const float4*)&kle[t * 64 + u4 * 4];
            const float4 wv = *(const float4*)&W2[j * 192 + 128 + u4 * 4];
            acc += kv.x * wv.x + kv.y * wv.y + kv.z * wv.z + kv.w * wv.w;
        }
        E2i[((j >> 2) * 128 + t) * 4 + (j & 3)] = fexp2(-LOG2E * acc);
    }
}

// ---------------------------------------------------------------------------
// K_PREP: 8 batch elems/block, 512 threads, grid 512. All threads used:
// ug = t>>8 splits the u-accumulation range; ug1 writes partials to ps[],
// ug0 combines + sigmoid. Output: es{1,2}o[b][j] = exp2(-log2e * s{1,2}[b][j])
// ---------------------------------------------------------------------------
__global__ __launch_bounds__(512, 4) void k_prep(
    const int*   __restrict__ stu_id,
    const int*   __restrict__ exer_id,
    const float* __restrict__ student_emb,   // (2*50000, 64) flat
    const float* __restrict__ prompt_stu,    // (50000, 64)
    const float* __restrict__ k_diff,        // (20000, 64)
    const float* __restrict__ s_exer,        // (2, 64)
    const float* __restrict__ kle4,
    const float* __restrict__ fc1i,
    const float* __restrict__ fc2i,
    const float* __restrict__ W1ai,
    const float* __restrict__ W2ai,
    const float* __restrict__ fc1_b,
    const float* __restrict__ fc2_b,
    float* __restrict__ es1o,                // (B,128)
    float* __restrict__ es2o)
{
    __shared__ __align__(16) float sh_in [4][64][8];    // 8 KB
    __shared__ __align__(16) float sh_old[2][128][8];   // 8 KB
    __shared__ __align__(16) float sh_e  [2][128][8];   // 8 KB
    __shared__ __align__(16) float ps    [2][8][128];   // 8 KB  [half][b][idx]

    const int t  = threadIdx.x;           // 0..511
    const int b0 = blockIdx.x * 8;

    // ---- gather phase: 64 threads per local batch elem, coalesced ----
    {
        const int g   = t >> 6;
        const int u   = t & 63;
        const int sid = stu_id[b0 + g];
        const int eid = exer_id[b0 + g];
        const int er  = (eid >= 10000) ? 1 : 0;
        sh_in[0][u][g] = student_emb[sid * 64 + u];
        sh_in[1][u][g] = fsig(k_diff[eid * 64 + u]);
        sh_in[2][u][g] = prompt_stu[(sid % STUN) * 64 + u];
        sh_in[3][u][g] = fsig(s_exer[er * 64 + u]);
    }
    __syncthreads();

    const int ug   = t >> 8;              // u-range group
    const int tt   = t & 255;
    const int half = tt >> 7;
    const int idx  = tt & 127;

    float acc[8];

#define FMA8(xbase) { \
        const float4 x0 = *(const float4*)&(xbase)[0]; \
        const float4 x1 = *(const float4*)&(xbase)[4]; \
        acc[0] += wv * x0.x; acc[1] += wv * x0.y; acc[2] += wv * x0.z; acc[3] += wv * x0.w; \
        acc[4] += wv * x1.x; acc[5] += wv * x1.y; acc[6] += wv * x1.z; acc[7] += wv * x1.w; }

#define WSTEP(WARR, XARR, u4) { \
        const float4 w4 = *(const float4*)&WARR[((u4) * 128 + idx) * 4]; \
        { const float wv = w4.x; FMA8(XARR[(u4)*4+0]); } \
        { const float wv = w4.y; FMA8(XARR[(u4)*4+1]); } \
        { const float wv = w4.z; FMA8(XARR[(u4)*4+2]); } \
        { const float wv = w4.w; FMA8(XARR[(u4)*4+3]); } }

#define WSTEPO(WARR, XARR, u4, uoff) { \
        const float4 w4 = *(const float4*)&WARR[((u4) * 128 + idx) * 4]; \
        { const float wv = w4.x; FMA8(XARR[((u4)-(uoff))*4+0]); } \
        { const float wv = w4.y; FMA8(XARR[((u4)-(uoff))*4+1]); } \
        { const float wv = w4.z; FMA8(XARR[((u4)-(uoff))*4+2]); } \
        { const float wv = w4.w; FMA8(XARR[((u4)-(uoff))*4+3]); } }

    // ---- stage 1: old[k] = sig( dot(row, kle[k]) ), u-split ----
    #pragma unroll
    for (int b = 0; b < 8; ++b) acc[b] = 0.f;
    {
        const int u4a = ug * 8;
        #pragma unroll 4
        for (int u4 = u4a; u4 < u4a + 8; ++u4) WSTEP(kle4, sh_in[half], u4);
    }
    if (ug == 1) {
        #pragma unroll
        for (int b = 0; b < 8; ++b) ps[half][b][idx] = acc[b];
    }
    __syncthreads();
    if (ug == 0) {
        #pragma unroll
        for (int b = 0; b < 8; ++b)
            sh_old[half][idx][b] = fsig(acc[b] + ps[half][b][idx]);
    }
    __syncthreads();

    // ---- stage 2: e[i] = sig( [p, old] @ fcW[i] + fcb[i] ), u-split ----
    #pragma unroll
    for (int b = 0; b < 8; ++b) acc[b] = 0.f;
    {
        const float* fcT = half ? fc2i : fc1i;
        if (ug == 0) {
            #pragma unroll 4
            for (int u4 = 0; u4 < 16; ++u4) WSTEP(fcT, sh_in[2 + half], u4);
            #pragma unroll 4
            for (int u4 = 16; u4 < 24; ++u4) WSTEPO(fcT, sh_old[half], u4, 16);
        } else {
            #pragma unroll 4
            for (int u4 = 24; u4 < 48; ++u4) WSTEPO(fcT, sh_old[half], u4, 16);
        }
    }
    if (ug == 1) {
        #pragma unroll
        for (int b = 0; b < 8; ++b) ps[half][b][idx] = acc[b];
    }
    __syncthreads();
    if (ug == 0) {
        const float bias = (half ? fc2_b : fc1_b)[idx];
        #pragma unroll
        for (int b = 0; b < 8; ++b)
            sh_e[half][idx][b] = fsig(acc[b] + ps[half][b][idx] + bias);
    }
    __syncthreads();

    // ---- stage 3: es[j] = exp2(-log2e * dot(e, Wa[j])), u-split -> global ----
    #pragma unroll
    for (int b = 0; b < 8; ++b) acc[b] = 0.f;
    {
        const float* WT = half ? W2ai : W1ai;
        const int u4a = ug * 16;
        #pragma unroll 4
        for (int u4 = u4a; u4 < u4a + 16; ++u4) WSTEP(WT, sh_e[half], u4);
    }
    if (ug == 1) {
        #pragma unroll
        for (int b = 0; b < 8; ++b) ps[half][b][idx] = acc[b];
    }
    __syncthreads();
    if (ug == 0) {
        float* eso = half ? es2o : es1o;
        #pragma unroll
        for (int b = 0; b < 8; ++b)
            eso[(b0 + b) * 128 + idx] = fexp2(-LOG2E * (acc[b] + ps[half][b][idx]));
    }
#undef FMA8
#undef WSTEP
#undef WSTEPO
}

// ---------------------------------------------------------------------------
// K_MAIN: 2 batch elems/block, 256 threads (4 waves), grid 2048.
// wave w: kh=w&1 (k-half), jh=w>>1 (j-half). Thread: 2 b x 64 j x 1 k.
// Per pair: u = es1*E1, v = es2*E2, acc += (v-u)*rcp((1+u)(1+v))*w3
// -> 8 VALU + 1 rcp per pair (trans-pipe relieved 3x).
// LDS ~4.2 KB; launch_bounds(256,6) -> 6 blocks/CU, 24 waves/CU.
// ---------------------------------------------------------------------------
__global__ __launch_bounds__(256, 6) void k_main(
    const float* __restrict__ es1o,
    const float* __restrict__ es2o,
    const float* __restrict__ E1i,    // [j4=32][k=128][4] = exp2(A1')
    const float* __restrict__ E2i,
    const float* __restrict__ W3,
    const float* __restrict__ b3,
    const float* __restrict__ kn,
    float* __restrict__ out)
{
    __shared__ __align__(16) float ses[2][2][128];   // [mat][b][j]  2 KB
    __shared__ float sW3[128];
    __shared__ __align__(16) float redj[2][64][2];   // [kh][lane][b] 1 KB
    __shared__ float red2_o[2][2];
    __shared__ float red2_k[2][2];

    const int t   = threadIdx.x;          // 0..255
    const int b0  = blockIdx.x * 2;

    // ---- stage es rows + W3 into LDS ----
    if (t < 128) {
        const int row  = t >> 5;          // 0..3: es1/b0, es1/b1, es2/b0, es2/b1
        const int col4 = (t & 31) * 4;
        const float* src = (row < 2) ? es1o : es2o;
        *(float4*)&ses[row >> 1][row & 1][col4] =
            *(const float4*)&src[(b0 + (row & 1)) * 128 + col4];
    } else if (t < 160) {
        const int q = t - 128;
        *(float4*)&sW3[q * 4] = *(const float4*)&W3[q * 4];
    }
    __syncthreads();

    const int w   = t >> 6;
    const int kk  = t & 63;
    const int kh  = w & 1;
    const int jh  = w >> 1;
    const int k2  = kh * 64 + kk;

    const float4* E1v = (const float4*)E1i;   // [j4*128 + k]
    const float4* E2v = (const float4*)E2i;

    float acc0 = 0.f, acc1 = 0.f;

#define COMP(acc, esv1, esv2, e1c, e2c, w3c) { \
        const float uu = (esv1) * (e1c); \
        const float vv = (esv2) * (e2c); \
        const float dd = frcp((1.f + uu) * (1.f + vv)); \
        acc += ((vv - uu) * dd) * (w3c); }

    #pragma unroll 4
    for (int j4 = 0; j4 < 16; ++j4) {
        const int jj4 = jh * 16 + j4;
        const int j   = jj4 * 4;
        const float4 e1  = E1v[jj4 * 128 + k2];
        const float4 e2  = E2v[jj4 * 128 + k2];
        const float4 w3  = *(const float4*)&sW3[j];
        const float4 s1a = *(const float4*)&ses[0][0][j];
        const float4 s1b = *(const float4*)&ses[0][1][j];
        const float4 s2a = *(const float4*)&ses[1][0][j];
        const float4 s2b = *(const float4*)&ses[1][1][j];

        COMP(acc0, s1a.x, s2a.x, e1.x, e2.x, w3.x);
        COMP(acc0, s1a.y, s2a.y, e1.y, e2.y, w3.y);
        COMP(acc0, s1a.z, s2a.z, e1.z, e2.z, w3.z);
        COMP(acc0, s1a.w, s2a.w, e1.w, e2.w, w3.w);
        COMP(acc1, s1b.x, s2b.x, e1.x, e2.x, w3.x);
        COMP(acc1, s1b.y, s2b.y, e1.y, e2.y, w3.y);
        COMP(acc1, s1b.z, s2b.z, e1.z, e2.z, w3.z);
        COMP(acc1, s1b.w, s2b.w, e1.w, e2.w, w3.w);
    }
#undef COMP

    // ---- epilogue: combine j-halves, outer sigmoid, kn-weighted k-mean ----
    if (jh == 1) {
        redj[kh][kk][0] = acc0;
        redj[kh][kk][1] = acc1;
    }
    __syncthreads();
    if (jh == 0) {
        const float bb3 = b3[0];
        const float t0 = acc0 + redj[kh][kk][0];
        const float t1 = acc1 + redj[kh][kk][1];
        const float o0 = fsig(t0 + bb3);
        const float o1 = fsig(t1 + bb3);
        const float kn0 = kn[(b0 + 0) * 128 + k2];
        const float kn1 = kn[(b0 + 1) * 128 + k2];
        float co0 = o0 * kn0, ck0 = kn0;
        float co1 = o1 * kn1, ck1 = kn1;
        #pragma unroll
        for (int off = 1; off < 64; off <<= 1) {
            co0 += __shfl_xor(co0, off);
            ck0 += __shfl_xor(ck0, off);
            co1 += __shfl_xor(co1, off);
            ck1 += __shfl_xor(ck1, off);
        }
        if (kk == 0) {
            red2_o[kh][0] = co0; red2_o[kh][1] = co1;
            red2_k[kh][0] = ck0; red2_k[kh][1] = ck1;
        }
    }
    __syncthreads();
    if (t < 2) {
        const float so = red2_o[0][t] + red2_o[1][t];
        const float sk = red2_k[0][t] + red2_k[1][t];
        out[b0 + t] = so / sk;
    }
}

// ---------------------------------------------------------------------------
extern "C" void kernel_launch(void* const* d_in, const int* in_sizes, int n_in,
                              void* d_out, int out_size, void* d_ws, size_t ws_size,
                              hipStream_t stream)
{
    const int*   stu_id      = (const int*)  d_in[0];
    const int*   exer_id     = (const int*)  d_in[1];
    const float* kn_emb      = (const float*)d_in[2];
    const float* student_emb = (const float*)d_in[3];
    const float* prompt_stu  = (const float*)d_in[4];
    const float* kle         = (const float*)d_in[5];
    const float* k_diff      = (const float*)d_in[6];
    const float* s_exer      = (const float*)d_in[7];
    const float* W1          = (const float*)d_in[8];
    const float* W2          = (const float*)d_in[9];
    const float* W3          = (const float*)d_in[10];
    const float* b3          = (const float*)d_in[11];
    const float* fc1_W       = (const float*)d_in[12];
    const float* fc1_b       = (const float*)d_in[13];
    const float* fc2_W       = (const float*)d_in[14];
    const float* fc2_b       = (const float*)d_in[15];
    float* out = (float*)d_out;

    float* ws   = (float*)d_ws;
    float* kle4 = ws;                        // 16*128*4  = 8192
    float* fc1i = kle4 + 8192;               // 48*128*4  = 24576
    float* fc2i = fc1i + 24576;
    float* W1ai = fc2i + 24576;              // 32*128*4  = 16384
    float* W2ai = W1ai + 16384;
    float* E1i  = W2ai + 16384;              // 32*128*4  = 16384
    float* E2i  = E1i  + 16384;
    float* es1o = E2i  + 16384;              // 4096*128
    float* es2o = es1o + BATCH * 128;

    k_pre<<<432, 128, 0, stream>>>(kle, W1, W2, fc1_W, fc2_W,
                                   kle4, fc1i, fc2i, W1ai, W2ai, E1i, E2i);
    k_prep<<<BATCH / 8, 512, 0, stream>>>(stu_id, exer_id, student_emb, prompt_stu,
                                          k_diff, s_exer, kle4, fc1i, fc2i,
                                          W1ai, W2ai, fc1_b, fc2_b, es1o, es2o);
    k_main<<<BATCH / 2, 256, 0, stream>>>(es1o, es2o, E1i, E2i, W3, b3, kn_emb, out);
}